// Round 3
// baseline (744.606 us; speedup 1.0000x reference)
//
#include <hip/hip_runtime.h>
#include <hip/hip_bf16.h>

#define BATCH 2
#define SEQ 2048
#define EMBED 1024
#define NHEADS 16
#define HDIM 64

typedef __hip_bfloat16 bf16;
typedef __attribute__((ext_vector_type(8))) short bf16x8;   // 8 bf16 (4 VGPRs)
typedef __attribute__((ext_vector_type(4))) float f32x4;

typedef const __attribute__((address_space(1))) void* gaddr_t;
typedef __attribute__((address_space(3))) void* laddr_t;

// fused f32 -> bf16 (RNE) for x, qkv_w, proj_w in one launch
__global__ __launch_bounds__(256)
void f2b_all(const float* __restrict__ s0, bf16* __restrict__ d0, int n0,
             const float* __restrict__ s1, bf16* __restrict__ d1, int n1,
             const float* __restrict__ s2, bf16* __restrict__ d2, int n2)
{
    int i = blockIdx.x * 256 + threadIdx.x;
    const float* s; bf16* d;
    if (i < n0)                { s = s0; d = d0; }
    else if ((i -= n0) < n1)   { s = s1; d = d1; }
    else if ((i -= n1) < n2)   { s = s2; d = d2; }
    else return;
    const float4 v = ((const float4*)s)[i];
    union { ushort4 u4; bf16 h[4]; } o;
    o.h[0] = __float2bfloat16(v.x);
    o.h[1] = __float2bfloat16(v.y);
    o.h[2] = __float2bfloat16(v.z);
    o.h[3] = __float2bfloat16(v.w);
    ((ushort4*)d)[i] = o.u4;
}

// C = A(M,K) @ B(N,K)^T + bias(N), bf16 in, fp32 accum, f32 bias.
// MODE 0: C = float*, row-major (M,N).
// MODE 1: QKV scatter: Q,K -> [b][h][s][d]; V -> TRANSPOSED [b][h][d][s].
// NT: number of 16-wide n-tiles per wave; block N-tile = NT*32.
//     NT=4 -> 128x128 tile (m97 structure); NT=2 -> 128x64 tile
//     (2x the blocks for occupancy-starved small-N GEMMs).
template<int MODE, int NT>
__global__ __launch_bounds__(256)
void gemm_bt(const bf16* __restrict__ A, const bf16* __restrict__ B,
             const float* __restrict__ bias, void* __restrict__ Cv,
             int M, int N, int K)
{
    constexpr int BN = NT * 32;
    __shared__ __align__(16) bf16 lA[128 * 32];
    __shared__ __align__(16) bf16 lB[BN * 32];
    const int tid  = threadIdx.x;
    const int bn   = blockIdx.x, bm = blockIdx.y;
    const int wave = tid >> 6, lane = tid & 63;
    const int wm   = (wave >> 1) << 6, wn = (wave & 1) * (NT << 4);
    const int quad = lane >> 4, l16 = lane & 15;

    f32x4 acc[4][NT] = {};

    for (int kt = 0; kt < K; kt += 32) {
        __syncthreads();
        #pragma unroll
        for (int i = 0; i < 2; ++i) {
            const int c = tid + (i << 8);            // 16B chunks
            const int r = c >> 2, kc = (c & 3) << 3; // row, k-col(8 bf16)
            const bf16* gA = A + (long)(bm * 128 + r) * K + (kt + kc);
            __builtin_amdgcn_global_load_lds((gaddr_t)gA, (laddr_t)&lA[c << 3], 16, 0, 0);
            if (c < BN * 4) {                        // wave-uniform for NT=2 (i==0 only)
                const bf16* gB = B + (long)(bn * BN + r) * K + (kt + kc);
                __builtin_amdgcn_global_load_lds((gaddr_t)gB, (laddr_t)&lB[c << 3], 16, 0, 0);
            }
        }
        __syncthreads();

        bf16x8 af[4], bfr[NT];
        #pragma unroll
        for (int t = 0; t < 4; ++t)
            af[t]  = *(const bf16x8*)&lA[(wm + t * 16 + l16) * 32 + quad * 8];
        #pragma unroll
        for (int t = 0; t < NT; ++t)
            bfr[t] = *(const bf16x8*)&lB[(wn + t * 16 + l16) * 32 + quad * 8];
        #pragma unroll
        for (int tm = 0; tm < 4; ++tm)
            #pragma unroll
            for (int tn = 0; tn < NT; ++tn)
                acc[tm][tn] = __builtin_amdgcn_mfma_f32_16x16x32_bf16(
                    af[tm], bfr[tn], acc[tm][tn], 0, 0, 0);
    }

    #pragma unroll
    for (int tm = 0; tm < 4; ++tm) {
        #pragma unroll
        for (int tn = 0; tn < NT; ++tn) {
            const int gn = bn * BN + wn + tn * 16 + l16;
            const float bv = bias[gn];
            if (MODE == 0) {
                #pragma unroll
                for (int r = 0; r < 4; ++r) {
                    const int gm = bm * 128 + wm + tm * 16 + quad * 4 + r;
                    ((float*)Cv)[(long)gm * N + gn] = acc[tm][tn][r] + bv;
                }
            } else {
                const int part = gn >> 10, h = (gn >> 6) & (NHEADS - 1), d = gn & (HDIM - 1);
                const int gm0 = bm * 128 + wm + tm * 16 + quad * 4;   // 4 consecutive rows
                const int b = gm0 >> 11, s0 = gm0 & (SEQ - 1);
                if (part == 2) {
                    // V transposed: [b][h][d][s], 4 consecutive s per lane -> short4
                    union { ushort4 u4; bf16 hv[4]; } o;
                    #pragma unroll
                    for (int r = 0; r < 4; ++r) o.hv[r] = __float2bfloat16(acc[tm][tn][r] + bv);
                    const long off = ((((long)2 * BATCH + b) * NHEADS + h) * HDIM + d) * SEQ + s0;
                    *(ushort4*)((bf16*)Cv + off) = o.u4;
                } else {
                    #pragma unroll
                    for (int r = 0; r < 4; ++r) {
                        const long off = ((((long)part * BATCH + b) * NHEADS + h) * SEQ + (s0 + r)) * HDIM + d;
                        ((bf16*)Cv)[off] = __float2bfloat16(acc[tm][tn][r] + bv);
                    }
                }
            }
        }
    }
}

// Barrier-free flash attention, key-split x2 for TLP (4096 waves = 4/SIMD)
// and XCD-affine grid (blockIdx.x = bh -> flat%8 = bh%8 -> one XCD per bh).
// Wave = 32 queries; K/V direct from global (L2-hot); V^T for coalesced PV.
//
// SWAPPED QK^T (T12 enabling trick): s = mfma(A=K-frag, B=Q-frag) -> C layout
// col=q=l15, row=key=quad*4+r. Each lane then holds 4 CONSECUTIVE KEYS at one
// query, so P lands in a plain row-major [32 q][72 key] wave-private LDS slab
// with 8x ds_write_b64 per tile (baseline: 32x scalar b16), and PV A-frags
// read back with 4x ds_read_b128. All plain C++ LDS ops -> compiler-ordered
// lgkmcnt, no barriers, no inline asm. lsum shrinks to 2 regs (reduce = 2
// shuffles over quads). Causal mask evaluated only on the diagonal tile
// (earlier tiles provably unmasked: kb+63 <= qw0-1). Emits unnormalized f32
// O-partials + partial denominators.
__global__ __launch_bounds__(256)
void attn_nf(const bf16* __restrict__ Q, const bf16* __restrict__ K,
             const bf16* __restrict__ Vt, float* __restrict__ Op,
             float* __restrict__ lp)
{
    __shared__ __align__(16) bf16 pS[4 * 32 * 72];   // per-wave P slab, 72 = 64+pad (16B rows)

    const int tid  = threadIdx.x;
    const int wave = tid >> 6, lane = tid & 63;
    const int quad = lane >> 4, l15 = lane & 15;
    const int bh   = blockIdx.x;                     // XCD affinity: flat%8 = bh%8
    const int half = blockIdx.y >> 4;
    const int qidx = blockIdx.y & 15;
    const int qg   = (15 - qidx) * 4 + wave;         // heaviest first
    const int qw0  = qg * 32;

    const bf16* Qb  = Q  + (long)bh * SEQ * HDIM;
    const bf16* Kb  = K  + (long)bh * SEQ * HDIM;
    const bf16* Vtb = Vt + (long)bh * HDIM * SEQ;
    bf16* pW = pS + wave * 32 * 72;

    // Q B-frags [mt][c]: B[n=q=l15][k=c*32+quad*8+j]
    bf16x8 qf[2][2];
    #pragma unroll
    for (int mt = 0; mt < 2; ++mt)
        #pragma unroll
        for (int c = 0; c < 2; ++c) {
            union { int4 i; bf16x8 v; } u;
            u.i = *(const int4*)(Qb + (long)(qw0 + mt * 16 + l15) * HDIM + c * 32 + quad * 8);
            qf[mt][c] = u.v;
        }

    f32x4 acc[2][4] = {};          // unnormalized O (C layout: col=d, row=q)
    float lsum[2] = {};            // per-lane partial denominators (q = mt*16+l15)

    const int nkt = (qw0 >> 6) + 1;                      // full tile count for this wave
    const float sc = 0.125f * 1.44269504088896340736f;   // D^-0.5 * log2(e)

    for (int t = half; t < nkt; t += 2) {
        const int kb = t * 64;

        // --- S^T = K Q^T: s[mt][nt] col=q(l15), row=key(quad*4+r) ---
        f32x4 s[2][4] = {};
        #pragma unroll
        for (int c = 0; c < 2; ++c) {
            #pragma unroll
            for (int nt = 0; nt < 4; ++nt) {
                union { int4 i; bf16x8 v; } u;
                u.i = *(const int4*)(Kb + (long)(kb + nt * 16 + l15) * HDIM + c * 32 + quad * 8);
                __builtin_amdgcn_s_setprio(1);
                #pragma unroll
                for (int mt = 0; mt < 2; ++mt)
                    s[mt][nt] = __builtin_amdgcn_mfma_f32_16x16x32_bf16(
                        u.v, qf[mt][c], s[mt][nt], 0, 0, 0);
                __builtin_amdgcn_s_setprio(0);
            }
        }

        // --- softmax (fixed-reference) + row-major P to wave-private LDS ---
        const bool diag = (t == nkt - 1);                // only diagonal tile is masked
        #pragma unroll
        for (int mt = 0; mt < 2; ++mt)
            #pragma unroll
            for (int nt = 0; nt < 4; ++nt) {
                union { ushort4 u4; bf16 hv[4]; } o;
                #pragma unroll
                for (int r = 0; r < 4; ++r) {
                    float p = __builtin_amdgcn_exp2f(s[mt][nt][r] * sc);
                    if (diag) {
                        const int key = nt * 16 + quad * 4 + r;  // local key
                        const int qq  = mt * 16 + l15;           // local query
                        if ((kb + key) > (qw0 + qq)) p = 0.f;
                    }
                    lsum[mt] += p;
                    o.hv[r] = __float2bfloat16(p);
                }
                // P[q = mt*16+l15][key = nt*16+quad*4 .. +3] -> one b64 write
                *(ushort4*)&pW[(mt * 16 + l15) * 72 + nt * 16 + quad * 4] = o.u4;
            }

        // --- O += P V: pf = A[m=q][k=key] via b128 row reads; vf = B[n=d][k=key] ---
        #pragma unroll
        for (int c = 0; c < 2; ++c) {
            bf16x8 pf[2];
            #pragma unroll
            for (int mt = 0; mt < 2; ++mt)
                pf[mt] = *(const bf16x8*)&pW[(mt * 16 + l15) * 72 + c * 32 + quad * 8];
            #pragma unroll
            for (int nt = 0; nt < 4; ++nt) {
                union { int4 i; bf16x8 v; } u;
                u.i = *(const int4*)(Vtb + (long)(nt * 16 + l15) * SEQ + kb + c * 32 + quad * 8);
                __builtin_amdgcn_s_setprio(1);
                #pragma unroll
                for (int mt = 0; mt < 2; ++mt)
                    acc[mt][nt] = __builtin_amdgcn_mfma_f32_16x16x32_bf16(
                        pf[mt], u.v, acc[mt][nt], 0, 0, 0);
                __builtin_amdgcn_s_setprio(0);
            }
        }
    }

    // lsum[mt] holds this quad's key-partials; sum across the 4 quads (same l15)
    #pragma unroll
    for (int i = 0; i < 2; ++i) {
        lsum[i] += __shfl_xor(lsum[i], 16, 64);
        lsum[i] += __shfl_xor(lsum[i], 32, 64);
    }

    const long halfO = (long)BATCH * NHEADS * SEQ * HDIM;
    float* Oh = Op + half * halfO + ((long)bh * SEQ) * HDIM;
    float* lh = lp + half * (BATCH * NHEADS * SEQ) + bh * SEQ;
    #pragma unroll
    for (int mt = 0; mt < 2; ++mt) {
        #pragma unroll
        for (int r = 0; r < 4; ++r) {
            const int rl = mt * 16 + quad * 4 + r;
            float* orow = Oh + (long)(qw0 + rl) * HDIM;
            #pragma unroll
            for (int nt = 0; nt < 4; ++nt)
                orow[nt * 16 + l15] = acc[mt][nt][r];
        }
        if (quad == 0) lh[qw0 + mt * 16 + l15] = lsum[mt];
    }
}

// att[b][s][h*64+d] = (O0 + O1) / (l0 + l1), f32 -> bf16
__global__ __launch_bounds__(256)
void attn_combine(const float* __restrict__ Op, const float* __restrict__ lp,
                  bf16* __restrict__ att)
{
    const int i = blockIdx.x * 256 + threadIdx.x;      // over [bh][q][d/4]
    const int d4 = i & 15, q = (i >> 4) & (SEQ - 1), bh = i >> 15;
    const long halfO = (long)BATCH * NHEADS * SEQ * HDIM;
    const long rowo  = ((long)bh * SEQ + q) * HDIM;
    const float4 a = ((const float4*)(Op + rowo))[d4];
    const float4 b = ((const float4*)(Op + halfO + rowo))[d4];
    const int li = bh * SEQ + q;
    const float inv = 1.f / (lp[li] + lp[BATCH * NHEADS * SEQ + li]);
    const int bb = bh >> 4, h = bh & 15;
    union { ushort4 u4; bf16 hv[4]; } o;
    o.hv[0] = __float2bfloat16((a.x + b.x) * inv);
    o.hv[1] = __float2bfloat16((a.y + b.y) * inv);
    o.hv[2] = __float2bfloat16((a.z + b.z) * inv);
    o.hv[3] = __float2bfloat16((a.w + b.w) * inv);
    *(ushort4*)(att + ((long)bb * SEQ + q) * EMBED + h * HDIM + d4 * 4) = o.u4;
}

extern "C" void kernel_launch(void* const* d_in, const int* in_sizes, int n_in,
                              void* d_out, int out_size, void* d_ws, size_t ws_size,
                              hipStream_t stream)
{
    const float* x      = (const float*)d_in[0];
    // d_in[1] = mask: causal by construction, computed analytically — unused.
    const float* qkv_w  = (const float*)d_in[2];
    const float* qkv_b  = (const float*)d_in[3];
    const float* proj_w = (const float*)d_in[4];
    const float* proj_b = (const float*)d_in[5];
    float* out = (float*)d_out;

    const long nX  = (long)BATCH * SEQ * EMBED;     // 4,194,304
    const long nQW = 3L * EMBED * EMBED;            // 3,145,728
    const long nPW = (long)EMBED * EMBED;           // 1,048,576
    const long per = (long)BATCH * NHEADS * SEQ * HDIM;  // 4,194,304

    bf16* xw  = (bf16*)d_ws;          // x in bf16
    bf16* qwm = xw + nX;              // qkv_w bf16
    bf16* pwm = qwm + nQW;            // proj_w bf16
    bf16* qw  = pwm + nPW;            // Q [b][h][s][d]
    bf16* kw  = qw + per;             // K [b][h][s][d]
    bf16* vw  = kw + per;             // V TRANSPOSED [b][h][d][s]
    bf16* att = vw + per;             // (B*S, E) bf16 row-major
    float* Op = (float*)(att + per);  // 2 x per f32 (O partials)
    float* lp = Op + 2 * per;         // 2 x B*H*S f32 (l partials)

    // 0) f32 -> bf16 conversions (single launch)
    const int n0 = (int)(nX / 4), n1 = (int)(nQW / 4), n2 = (int)(nPW / 4);
    f2b_all<<<(n0 + n1 + n2 + 255) / 256, 256, 0, stream>>>(
        x, xw, n0, qkv_w, qwm, n1, proj_w, pwm, n2);

    // 1) QKV: (B*S,E) @ (3E,E)^T + b, scattered (V transposed); 128x128 tile
    gemm_bt<1, 4><<<dim3(3 * EMBED / 128, BATCH * SEQ / 128), 256, 0, stream>>>(
        xw, qwm, qkv_b, qw, BATCH * SEQ, 3 * EMBED, EMBED);

    // 2) barrier-free causal attention (key-split x2, XCD-affine) + combine
    attn_nf<<<dim3(BATCH * NHEADS, 32), 256, 0, stream>>>(qw, kw, vw, Op, lp);
    attn_combine<<<(int)(per / 4 / 256), 256, 0, stream>>>(Op, lp, att);

    // 3) out(f32) = att @ proj_w^T + proj_b; 128x64 tile -> 512 blocks (2/CU)
    gemm_bt<0, 2><<<dim3(EMBED / 64, BATCH * SEQ / 128), 256, 0, stream>>>(
        att, pwm, proj_b, out, BATCH * SEQ, EMBED, EMBED);
}

// Round 4
// 740.676 us; speedup vs baseline: 1.0053x; 1.0053x over previous
//
#include <hip/hip_runtime.h>
#include <hip/hip_bf16.h>

#define BATCH 2
#define SEQ 2048
#define EMBED 1024
#define NHEADS 16
#define HDIM 64

typedef __hip_bfloat16 bf16;
typedef __attribute__((ext_vector_type(8))) short bf16x8;   // 8 bf16 (4 VGPRs)
typedef __attribute__((ext_vector_type(4))) float f32x4;

typedef const __attribute__((address_space(1))) void* gaddr_t;
typedef __attribute__((address_space(3))) void* laddr_t;

// fused f32 -> bf16 (RNE) for x, qkv_w, proj_w in one launch
__global__ __launch_bounds__(256)
void f2b_all(const float* __restrict__ s0, bf16* __restrict__ d0, int n0,
             const float* __restrict__ s1, bf16* __restrict__ d1, int n1,
             const float* __restrict__ s2, bf16* __restrict__ d2, int n2)
{
    int i = blockIdx.x * 256 + threadIdx.x;
    const float* s; bf16* d;
    if (i < n0)                { s = s0; d = d0; }
    else if ((i -= n0) < n1)   { s = s1; d = d1; }
    else if ((i -= n1) < n2)   { s = s2; d = d2; }
    else return;
    const float4 v = ((const float4*)s)[i];
    union { ushort4 u4; bf16 h[4]; } o;
    o.h[0] = __float2bfloat16(v.x);
    o.h[1] = __float2bfloat16(v.y);
    o.h[2] = __float2bfloat16(v.z);
    o.h[3] = __float2bfloat16(v.w);
    ((ushort4*)d)[i] = o.u4;
}

// C = A(M,K) @ B(N,K)^T + bias(N), bf16 in, fp32 accum, f32 bias.
// MODE 0: C = float*, row-major (M,N).
// MODE 1: QKV scatter: Q,K -> [b][h][s][d]; V -> TRANSPOSED [b][h][d][s].
// NT: n-tiles per wave; block N-tile = NT*32. NT=4 -> 128x128 (m97 structure).
// (R3 tried NT=2 for the proj GEMM: net-neutral-to-negative — 2x A-panel
//  re-reads cancel the occupancy gain. Reverted to NT=4 everywhere.)
template<int MODE, int NT>
__global__ __launch_bounds__(256)
void gemm_bt(const bf16* __restrict__ A, const bf16* __restrict__ B,
             const float* __restrict__ bias, void* __restrict__ Cv,
             int M, int N, int K)
{
    constexpr int BN = NT * 32;
    __shared__ __align__(16) bf16 lA[128 * 32];
    __shared__ __align__(16) bf16 lB[BN * 32];
    const int tid  = threadIdx.x;
    const int bn   = blockIdx.x, bm = blockIdx.y;
    const int wave = tid >> 6, lane = tid & 63;
    const int wm   = (wave >> 1) << 6, wn = (wave & 1) * (NT << 4);
    const int quad = lane >> 4, l16 = lane & 15;

    f32x4 acc[4][NT] = {};

    for (int kt = 0; kt < K; kt += 32) {
        __syncthreads();
        #pragma unroll
        for (int i = 0; i < 2; ++i) {
            const int c = tid + (i << 8);            // 16B chunks
            const int r = c >> 2, kc = (c & 3) << 3; // row, k-col(8 bf16)
            const bf16* gA = A + (long)(bm * 128 + r) * K + (kt + kc);
            __builtin_amdgcn_global_load_lds((gaddr_t)gA, (laddr_t)&lA[c << 3], 16, 0, 0);
            if (c < BN * 4) {                        // always true for NT=4
                const bf16* gB = B + (long)(bn * BN + r) * K + (kt + kc);
                __builtin_amdgcn_global_load_lds((gaddr_t)gB, (laddr_t)&lB[c << 3], 16, 0, 0);
            }
        }
        __syncthreads();

        bf16x8 af[4], bfr[NT];
        #pragma unroll
        for (int t = 0; t < 4; ++t)
            af[t]  = *(const bf16x8*)&lA[(wm + t * 16 + l16) * 32 + quad * 8];
        #pragma unroll
        for (int t = 0; t < NT; ++t)
            bfr[t] = *(const bf16x8*)&lB[(wn + t * 16 + l16) * 32 + quad * 8];
        #pragma unroll
        for (int tm = 0; tm < 4; ++tm)
            #pragma unroll
            for (int tn = 0; tn < NT; ++tn)
                acc[tm][tn] = __builtin_amdgcn_mfma_f32_16x16x32_bf16(
                    af[tm], bfr[tn], acc[tm][tn], 0, 0, 0);
    }

    #pragma unroll
    for (int tm = 0; tm < 4; ++tm) {
        #pragma unroll
        for (int tn = 0; tn < NT; ++tn) {
            const int gn = bn * BN + wn + tn * 16 + l16;
            const float bv = bias[gn];
            if (MODE == 0) {
                #pragma unroll
                for (int r = 0; r < 4; ++r) {
                    const int gm = bm * 128 + wm + tm * 16 + quad * 4 + r;
                    ((float*)Cv)[(long)gm * N + gn] = acc[tm][tn][r] + bv;
                }
            } else {
                const int part = gn >> 10, h = (gn >> 6) & (NHEADS - 1), d = gn & (HDIM - 1);
                const int gm0 = bm * 128 + wm + tm * 16 + quad * 4;   // 4 consecutive rows
                const int b = gm0 >> 11, s0 = gm0 & (SEQ - 1);
                if (part == 2) {
                    // V transposed: [b][h][d][s], 4 consecutive s per lane -> short4
                    union { ushort4 u4; bf16 hv[4]; } o;
                    #pragma unroll
                    for (int r = 0; r < 4; ++r) o.hv[r] = __float2bfloat16(acc[tm][tn][r] + bv);
                    const long off = ((((long)2 * BATCH + b) * NHEADS + h) * HDIM + d) * SEQ + s0;
                    *(ushort4*)((bf16*)Cv + off) = o.u4;
                } else {
                    #pragma unroll
                    for (int r = 0; r < 4; ++r) {
                        const long off = ((((long)part * BATCH + b) * NHEADS + h) * SEQ + (s0 + r)) * HDIM + d;
                        ((bf16*)Cv)[off] = __float2bfloat16(acc[tm][tn][r] + bv);
                    }
                }
            }
        }
    }
}

// Barrier-free flash attention, key-split x2 for TLP (4096 waves = 4/SIMD)
// and XCD-affine grid (blockIdx.x = bh -> flat%8 = bh%8 -> one XCD per bh).
// Wave = 32 queries; K/V direct from global (L2-hot: per-XCD working set
// ~2 MB < 4 MiB L2); V^T for coalesced PV.
//
// SWAPPED QK^T: s = mfma(A=K-frag, B=Q-frag) -> C layout col=q=l15,
// row=key=quad*4+r. Each lane holds 4 CONSECUTIVE KEYS at one query, so P
// lands row-major in a [32 q][72 key] wave-private LDS slab with 8x
// ds_write_b64 per tile (old: 32x scalar b16), read back as PV A-frags with
// 4x ds_read_b128. Plain C++ LDS ops -> compiler-ordered lgkmcnt, no
// barriers, no inline asm. lsum = 2 regs (reduce = 2 shuffles). Causal mask
// only on the diagonal tile (earlier tiles provably unmasked: kb+63 <= qw0-1).
// NO setprio: R3 showed fine-grained setprio toggles regress this kernel
// (they fence the compiler's load/MFMA interleave that hides L2 latency).
// Emits unnormalized f32 O-partials + partial denominators.
__global__ __launch_bounds__(256)
void attn_nf(const bf16* __restrict__ Q, const bf16* __restrict__ K,
             const bf16* __restrict__ Vt, float* __restrict__ Op,
             float* __restrict__ lp)
{
    __shared__ __align__(16) bf16 pS[4 * 32 * 72];   // per-wave P slab, 72 = 64+pad

    const int tid  = threadIdx.x;
    const int wave = tid >> 6, lane = tid & 63;
    const int quad = lane >> 4, l15 = lane & 15;
    const int bh   = blockIdx.x;                     // XCD affinity: flat%8 = bh%8
    const int half = blockIdx.y >> 4;
    const int qidx = blockIdx.y & 15;
    const int qg   = (15 - qidx) * 4 + wave;         // heaviest first
    const int qw0  = qg * 32;

    const bf16* Qb  = Q  + (long)bh * SEQ * HDIM;
    const bf16* Kb  = K  + (long)bh * SEQ * HDIM;
    const bf16* Vtb = Vt + (long)bh * HDIM * SEQ;
    bf16* pW = pS + wave * 32 * 72;

    // Q B-frags [mt][c]: B[n=q=l15][k=c*32+quad*8+j]
    bf16x8 qf[2][2];
    #pragma unroll
    for (int mt = 0; mt < 2; ++mt)
        #pragma unroll
        for (int c = 0; c < 2; ++c) {
            union { int4 i; bf16x8 v; } u;
            u.i = *(const int4*)(Qb + (long)(qw0 + mt * 16 + l15) * HDIM + c * 32 + quad * 8);
            qf[mt][c] = u.v;
        }

    f32x4 acc[2][4] = {};          // unnormalized O (C layout: col=d, row=q)
    float lsum[2] = {};            // per-lane partial denominators (q = mt*16+l15)

    const int nkt = (qw0 >> 6) + 1;                      // full tile count for this wave
    const float sc = 0.125f * 1.44269504088896340736f;   // D^-0.5 * log2(e)

    for (int t = half; t < nkt; t += 2) {
        const int kb = t * 64;

        // --- S^T = K Q^T: s[mt][nt] col=q(l15), row=key(quad*4+r) ---
        f32x4 s[2][4] = {};
        #pragma unroll
        for (int c = 0; c < 2; ++c) {
            #pragma unroll
            for (int nt = 0; nt < 4; ++nt) {
                union { int4 i; bf16x8 v; } u;
                u.i = *(const int4*)(Kb + (long)(kb + nt * 16 + l15) * HDIM + c * 32 + quad * 8);
                #pragma unroll
                for (int mt = 0; mt < 2; ++mt)
                    s[mt][nt] = __builtin_amdgcn_mfma_f32_16x16x32_bf16(
                        u.v, qf[mt][c], s[mt][nt], 0, 0, 0);
            }
        }

        // --- softmax (fixed-reference) + row-major P to wave-private LDS ---
        const bool diag = (t == nkt - 1);                // only diagonal tile is masked
        #pragma unroll
        for (int mt = 0; mt < 2; ++mt)
            #pragma unroll
            for (int nt = 0; nt < 4; ++nt) {
                union { ushort4 u4; bf16 hv[4]; } o;
                #pragma unroll
                for (int r = 0; r < 4; ++r) {
                    float p = __builtin_amdgcn_exp2f(s[mt][nt][r] * sc);
                    if (diag) {
                        const int key = nt * 16 + quad * 4 + r;  // local key
                        const int qq  = mt * 16 + l15;           // local query
                        if ((kb + key) > (qw0 + qq)) p = 0.f;
                    }
                    lsum[mt] += p;
                    o.hv[r] = __float2bfloat16(p);
                }
                // P[q = mt*16+l15][key = nt*16+quad*4 .. +3] -> one b64 write
                *(ushort4*)&pW[(mt * 16 + l15) * 72 + nt * 16 + quad * 4] = o.u4;
            }

        // --- O += P V: pf = A[m=q][k=key] via b128 row reads; vf = B[n=d][k=key] ---
        #pragma unroll
        for (int c = 0; c < 2; ++c) {
            bf16x8 pf[2];
            #pragma unroll
            for (int mt = 0; mt < 2; ++mt)
                pf[mt] = *(const bf16x8*)&pW[(mt * 16 + l15) * 72 + c * 32 + quad * 8];
            #pragma unroll
            for (int nt = 0; nt < 4; ++nt) {
                union { int4 i; bf16x8 v; } u;
                u.i = *(const int4*)(Vtb + (long)(nt * 16 + l15) * SEQ + kb + c * 32 + quad * 8);
                #pragma unroll
                for (int mt = 0; mt < 2; ++mt)
                    acc[mt][nt] = __builtin_amdgcn_mfma_f32_16x16x32_bf16(
                        pf[mt], u.v, acc[mt][nt], 0, 0, 0);
            }
        }
    }

    // lsum[mt] holds this quad's key-partials; sum across the 4 quads (same l15)
    #pragma unroll
    for (int i = 0; i < 2; ++i) {
        lsum[i] += __shfl_xor(lsum[i], 16, 64);
        lsum[i] += __shfl_xor(lsum[i], 32, 64);
    }

    const long halfO = (long)BATCH * NHEADS * SEQ * HDIM;
    float* Oh = Op + half * halfO + ((long)bh * SEQ) * HDIM;
    float* lh = lp + half * (BATCH * NHEADS * SEQ) + bh * SEQ;
    #pragma unroll
    for (int mt = 0; mt < 2; ++mt) {
        #pragma unroll
        for (int r = 0; r < 4; ++r) {
            const int rl = mt * 16 + quad * 4 + r;
            float* orow = Oh + (long)(qw0 + rl) * HDIM;
            #pragma unroll
            for (int nt = 0; nt < 4; ++nt)
                orow[nt * 16 + l15] = acc[mt][nt][r];
        }
        if (quad == 0) lh[qw0 + mt * 16 + l15] = lsum[mt];
    }
}

// att[b][s][h*64+d] = (O0 + O1) / (l0 + l1), f32 -> bf16
__global__ __launch_bounds__(256)
void attn_combine(const float* __restrict__ Op, const float* __restrict__ lp,
                  bf16* __restrict__ att)
{
    const int i = blockIdx.x * 256 + threadIdx.x;      // over [bh][q][d/4]
    const int d4 = i & 15, q = (i >> 4) & (SEQ - 1), bh = i >> 15;
    const long halfO = (long)BATCH * NHEADS * SEQ * HDIM;
    const long rowo  = ((long)bh * SEQ + q) * HDIM;
    const float4 a = ((const float4*)(Op + rowo))[d4];
    const float4 b = ((const float4*)(Op + halfO + rowo))[d4];
    const int li = bh * SEQ + q;
    const float inv = 1.f / (lp[li] + lp[BATCH * NHEADS * SEQ + li]);
    const int bb = bh >> 4, h = bh & 15;
    union { ushort4 u4; bf16 hv[4]; } o;
    o.hv[0] = __float2bfloat16((a.x + b.x) * inv);
    o.hv[1] = __float2bfloat16((a.y + b.y) * inv);
    o.hv[2] = __float2bfloat16((a.z + b.z) * inv);
    o.hv[3] = __float2bfloat16((a.w + b.w) * inv);
    *(ushort4*)(att + ((long)bb * SEQ + q) * EMBED + h * HDIM + d4 * 4) = o.u4;
}

extern "C" void kernel_launch(void* const* d_in, const int* in_sizes, int n_in,
                              void* d_out, int out_size, void* d_ws, size_t ws_size,
                              hipStream_t stream)
{
    const float* x      = (const float*)d_in[0];
    // d_in[1] = mask: causal by construction, computed analytically — unused.
    const float* qkv_w  = (const float*)d_in[2];
    const float* qkv_b  = (const float*)d_in[3];
    const float* proj_w = (const float*)d_in[4];
    const float* proj_b = (const float*)d_in[5];
    float* out = (float*)d_out;

    const long nX  = (long)BATCH * SEQ * EMBED;     // 4,194,304
    const long nQW = 3L * EMBED * EMBED;            // 3,145,728
    const long nPW = (long)EMBED * EMBED;           // 1,048,576
    const long per = (long)BATCH * NHEADS * SEQ * HDIM;  // 4,194,304

    bf16* xw  = (bf16*)d_ws;          // x in bf16
    bf16* qwm = xw + nX;              // qkv_w bf16
    bf16* pwm = qwm + nQW;            // proj_w bf16
    bf16* qw  = pwm + nPW;            // Q [b][h][s][d]
    bf16* kw  = qw + per;             // K [b][h][s][d]
    bf16* vw  = kw + per;             // V TRANSPOSED [b][h][d][s]
    bf16* att = vw + per;             // (B*S, E) bf16 row-major
    float* Op = (float*)(att + per);  // 2 x per f32 (O partials)
    float* lp = Op + 2 * per;         // 2 x B*H*S f32 (l partials)

    // 0) f32 -> bf16 conversions (single launch)
    const int n0 = (int)(nX / 4), n1 = (int)(nQW / 4), n2 = (int)(nPW / 4);
    f2b_all<<<(n0 + n1 + n2 + 255) / 256, 256, 0, stream>>>(
        x, xw, n0, qkv_w, qwm, n1, proj_w, pwm, n2);

    // 1) QKV: (B*S,E) @ (3E,E)^T + b, scattered (V transposed); 128x128 tile
    gemm_bt<1, 4><<<dim3(3 * EMBED / 128, BATCH * SEQ / 128), 256, 0, stream>>>(
        xw, qwm, qkv_b, qw, BATCH * SEQ, 3 * EMBED, EMBED);

    // 2) barrier-free causal attention (key-split x2, XCD-affine) + combine
    attn_nf<<<dim3(BATCH * NHEADS, 32), 256, 0, stream>>>(qw, kw, vw, Op, lp);
    attn_combine<<<(int)(per / 4 / 256), 256, 0, stream>>>(Op, lp, att);

    // 3) out(f32) = att @ proj_w^T + proj_b; 128x128 tile (R3's NT=2 reverted)
    gemm_bt<0, 4><<<dim3(EMBED / 128, BATCH * SEQ / 128), 256, 0, stream>>>(
        att, pwm, proj_b, out, BATCH * SEQ, EMBED, EMBED);
}

// Round 5
// 722.280 us; speedup vs baseline: 1.0309x; 1.0255x over previous
//
#include <hip/hip_runtime.h>
#include <hip/hip_bf16.h>

#define BATCH 2
#define SEQ 2048
#define EMBED 1024
#define NHEADS 16
#define HDIM 64

typedef __hip_bfloat16 bf16;
typedef __attribute__((ext_vector_type(8))) short bf16x8;   // 8 bf16 (4 VGPRs)
typedef __attribute__((ext_vector_type(4))) short bf16x4;
typedef __attribute__((ext_vector_type(4))) float f32x4;

typedef const __attribute__((address_space(1))) void* gaddr_t;
typedef __attribute__((address_space(3))) void* laddr_t;

__device__ __forceinline__ bf16x8 lds_frag8(const bf16* p) {
    const bf16x4 a = *(const bf16x4*)p;
    const bf16x4 b = *(const bf16x4*)(p + 4);
    return __builtin_shufflevector(a, b, 0, 1, 2, 3, 4, 5, 6, 7);
}

// fused f32 -> bf16 (RNE) for x, qkv_w, proj_w in one launch
__global__ __launch_bounds__(256)
void f2b_all(const float* __restrict__ s0, bf16* __restrict__ d0, int n0,
             const float* __restrict__ s1, bf16* __restrict__ d1, int n1,
             const float* __restrict__ s2, bf16* __restrict__ d2, int n2)
{
    int i = blockIdx.x * 256 + threadIdx.x;
    const float* s; bf16* d;
    if (i < n0)                { s = s0; d = d0; }
    else if ((i -= n0) < n1)   { s = s1; d = d1; }
    else if ((i -= n1) < n2)   { s = s2; d = d2; }
    else return;
    const float4 v = ((const float4*)s)[i];
    union { ushort4 u4; bf16 h[4]; } o;
    o.h[0] = __float2bfloat16(v.x);
    o.h[1] = __float2bfloat16(v.y);
    o.h[2] = __float2bfloat16(v.z);
    o.h[3] = __float2bfloat16(v.w);
    ((ushort4*)d)[i] = o.u4;
}

// C = A(M,K) @ B(N,K)^T + bias(N), bf16 in, fp32 accum, f32 bias.
// MODE 0: C = float*, row-major (M,N).
// MODE 1: QKV scatter: Q,K -> [b][h][s][d]; V -> TRANSPOSED [b][h][d][s].
// 128x128 tile (m97 structure).
// T1 XCD swizzle: flat block id -> (flat%8)*q + flat/8 (bijective when
// nwg%8==0; both our grids are 768 and 256 blocks). Each XCD then owns a
// contiguous bm-major chunk, so a 128-row A panel's consumer blocks share
// ONE XCD L2 instead of being round-robined across all 8.
template<int MODE>
__global__ __launch_bounds__(256)
void gemm_bt(const bf16* __restrict__ A, const bf16* __restrict__ B,
             const float* __restrict__ bias, void* __restrict__ Cv,
             int M, int N, int K)
{
    __shared__ __align__(16) bf16 lA[128 * 32];
    __shared__ __align__(16) bf16 lB[128 * 32];
    const int tid  = threadIdx.x;

    // --- XCD-chunk swizzle of the flat workgroup id (bijective, nwg%8==0) ---
    const int gx = gridDim.x;
    const int nwg = gx * gridDim.y;
    const int flat = blockIdx.y * gx + blockIdx.x;       // HW dispatch order: %8 = XCD
    const int q8 = nwg >> 3;
    const int nf = (flat & 7) * q8 + (flat >> 3);        // contiguous chunk per XCD
    const int bn = nf % gx, bm = nf / gx;

    const int wave = tid >> 6, lane = tid & 63;
    const int wm   = (wave >> 1) << 6, wn = (wave & 1) << 6;   // 2x2 waves of 64x64
    const int quad = lane >> 4, l16 = lane & 15;

    f32x4 acc[4][4] = {};

    for (int kt = 0; kt < K; kt += 32) {
        __syncthreads();
        #pragma unroll
        for (int i = 0; i < 2; ++i) {
            const int c = tid + (i << 8);            // 512 16B chunks per 128x32 tile
            const int r = c >> 2, kc = (c & 3) << 3; // row, k-col(8 bf16)
            const bf16* gA = A + (long)(bm * 128 + r) * K + (kt + kc);
            const bf16* gB = B + (long)(bn * 128 + r) * K + (kt + kc);
            __builtin_amdgcn_global_load_lds((gaddr_t)gA, (laddr_t)&lA[c << 3], 16, 0, 0);
            __builtin_amdgcn_global_load_lds((gaddr_t)gB, (laddr_t)&lB[c << 3], 16, 0, 0);
        }
        __syncthreads();

        bf16x8 af[4], bfr[4];
        #pragma unroll
        for (int t = 0; t < 4; ++t) {
            af[t]  = *(const bf16x8*)&lA[(wm + t * 16 + l16) * 32 + quad * 8];
            bfr[t] = *(const bf16x8*)&lB[(wn + t * 16 + l16) * 32 + quad * 8];
        }
        #pragma unroll
        for (int tm = 0; tm < 4; ++tm)
            #pragma unroll
            for (int tn = 0; tn < 4; ++tn)
                acc[tm][tn] = __builtin_amdgcn_mfma_f32_16x16x32_bf16(
                    af[tm], bfr[tn], acc[tm][tn], 0, 0, 0);
    }

    #pragma unroll
    for (int tm = 0; tm < 4; ++tm) {
        #pragma unroll
        for (int tn = 0; tn < 4; ++tn) {
            const int gn = bn * 128 + wn + tn * 16 + l16;
            const float bv = bias[gn];
            if (MODE == 0) {
                #pragma unroll
                for (int r = 0; r < 4; ++r) {
                    const int gm = bm * 128 + wm + tm * 16 + quad * 4 + r;
                    ((float*)Cv)[(long)gm * N + gn] = acc[tm][tn][r] + bv;
                }
            } else {
                const int part = gn >> 10, h = (gn >> 6) & (NHEADS - 1), d = gn & (HDIM - 1);
                const int gm0 = bm * 128 + wm + tm * 16 + quad * 4;   // 4 consecutive rows
                const int b = gm0 >> 11, s0 = gm0 & (SEQ - 1);
                if (part == 2) {
                    // V transposed: [b][h][d][s], 4 consecutive s per lane -> short4
                    union { ushort4 u4; bf16 hv[4]; } o;
                    #pragma unroll
                    for (int r = 0; r < 4; ++r) o.hv[r] = __float2bfloat16(acc[tm][tn][r] + bv);
                    const long off = ((((long)2 * BATCH + b) * NHEADS + h) * HDIM + d) * SEQ + s0;
                    *(ushort4*)((bf16*)Cv + off) = o.u4;
                } else {
                    #pragma unroll
                    for (int r = 0; r < 4; ++r) {
                        const long off = ((((long)part * BATCH + b) * NHEADS + h) * SEQ + (s0 + r)) * HDIM + d;
                        ((bf16*)Cv)[off] = __float2bfloat16(acc[tm][tn][r] + bv);
                    }
                }
            }
        }
    }
}

// Barrier-free flash attention, key-split x2 for TLP (4096 waves = 4/SIMD)
// and XCD-affine grid (blockIdx.x = bh -> flat%8 = bh%8 -> one XCD per bh).
// Wave = 32 queries; K/V direct from global (L2-hot); V^T for coalesced PV.
// Emits unnormalized f32 O-partials + partial denominators.
// NOTE (R3/R4 post-mortems): this kernel is latency-bound, not issue-bound.
// Both the swapped-QK packed-P rework (R3/R4, +15us) and fine-grained
// setprio (R3, +4us) REGRESSED it. This is the verbatim 725.4us baseline.
__global__ __launch_bounds__(256)
void attn_nf(const bf16* __restrict__ Q, const bf16* __restrict__ K,
             const bf16* __restrict__ Vt, float* __restrict__ Op,
             float* __restrict__ lp)
{
    __shared__ __align__(16) bf16 pS[4 * 32 * 68];   // per-wave P slab

    const int tid  = threadIdx.x;
    const int wave = tid >> 6, lane = tid & 63;
    const int quad = lane >> 4, l15 = lane & 15;
    const int bh   = blockIdx.x;                     // XCD affinity: flat%8 = bh%8
    const int half = blockIdx.y >> 4;
    const int qidx = blockIdx.y & 15;
    const int qg   = (15 - qidx) * 4 + wave;         // heaviest first
    const int qw0  = qg * 32;

    const bf16* Qb  = Q  + (long)bh * SEQ * HDIM;
    const bf16* Kb  = K  + (long)bh * SEQ * HDIM;
    const bf16* Vtb = Vt + (long)bh * HDIM * SEQ;
    bf16* pW = pS + wave * 32 * 68;

    // Q A-frags [mt][c]: A[m=l15][k=c*32+quad*8+j]
    bf16x8 qf[2][2];
    #pragma unroll
    for (int mt = 0; mt < 2; ++mt)
        #pragma unroll
        for (int c = 0; c < 2; ++c) {
            union { int4 i; bf16x8 v; } u;
            u.i = *(const int4*)(Qb + (long)(qw0 + mt * 16 + l15) * HDIM + c * 32 + quad * 8);
            qf[mt][c] = u.v;
        }

    f32x4 acc[2][4] = {};          // unnormalized O (C layout)
    float lsum[8] = {};            // per-lane partial denominators

    const int nkt = (qw0 >> 6) + 1;                      // full tile count for this wave
    const float sc = 0.125f * 1.44269504088896340736f;   // D^-0.5 * log2(e)

    for (int t = half; t < nkt; t += 2) {
        const int kb = t * 64;

        // --- S = Q K^T: kf = B[n=key][k=d], coalesced from [s][d] layout ---
        f32x4 s[2][4] = {};
        #pragma unroll
        for (int c = 0; c < 2; ++c) {
            #pragma unroll
            for (int nt = 0; nt < 4; ++nt) {
                union { int4 i; bf16x8 v; } u;
                u.i = *(const int4*)(Kb + (long)(kb + nt * 16 + l15) * HDIM + c * 32 + quad * 8);
                #pragma unroll
                for (int mt = 0; mt < 2; ++mt)
                    s[mt][nt] = __builtin_amdgcn_mfma_f32_16x16x32_bf16(
                        qf[mt][c], u.v, s[mt][nt], 0, 0, 0);
            }
        }

        // --- softmax (fixed-reference) + P to wave-private LDS ---
        #pragma unroll
        for (int mt = 0; mt < 2; ++mt)
            #pragma unroll
            for (int nt = 0; nt < 4; ++nt)
                #pragma unroll
                for (int r = 0; r < 4; ++r) {
                    const int rl = mt * 16 + quad * 4 + r;       // local q row
                    const int cl = nt * 16 + l15;                // local key col
                    const float p = ((kb + cl) <= (qw0 + rl))
                        ? __builtin_amdgcn_exp2f(s[mt][nt][r] * sc) : 0.f;
                    lsum[mt * 4 + r] += p;
                    pW[rl * 68 + cl] = __float2bfloat16(p);
                }

        // --- O += P V: vf = B[n=d][k=key], coalesced from V^T [d][s] layout ---
        #pragma unroll
        for (int c = 0; c < 2; ++c) {
            bf16x8 pf[2];
            #pragma unroll
            for (int mt = 0; mt < 2; ++mt)
                pf[mt] = lds_frag8(&pW[(mt * 16 + l15) * 68 + c * 32 + quad * 8]);
            #pragma unroll
            for (int nt = 0; nt < 4; ++nt) {
                union { int4 i; bf16x8 v; } u;
                u.i = *(const int4*)(Vtb + (long)(nt * 16 + l15) * SEQ + kb + c * 32 + quad * 8);
                #pragma unroll
                for (int mt = 0; mt < 2; ++mt)
                    acc[mt][nt] = __builtin_amdgcn_mfma_f32_16x16x32_bf16(
                        pf[mt], u.v, acc[mt][nt], 0, 0, 0);
            }
        }
    }

    // reduce lsum across the 16 key-lanes of each quad row-group
    #pragma unroll
    for (int i = 0; i < 8; ++i)
        #pragma unroll
        for (int m = 1; m < 16; m <<= 1) lsum[i] += __shfl_xor(lsum[i], m, 64);

    const long halfO = (long)BATCH * NHEADS * SEQ * HDIM;
    float* Oh = Op + half * halfO + ((long)bh * SEQ) * HDIM;
    float* lh = lp + half * (BATCH * NHEADS * SEQ) + bh * SEQ;
    #pragma unroll
    for (int mt = 0; mt < 2; ++mt)
        #pragma unroll
        for (int r = 0; r < 4; ++r) {
            const int rl = mt * 16 + quad * 4 + r;
            float* orow = Oh + (long)(qw0 + rl) * HDIM;
            #pragma unroll
            for (int nt = 0; nt < 4; ++nt)
                orow[nt * 16 + l15] = acc[mt][nt][r];
            if (l15 == 0) lh[qw0 + rl] = lsum[mt * 4 + r];
        }
}

// att[b][s][h*64+d] = (O0 + O1) / (l0 + l1), f32 -> bf16
__global__ __launch_bounds__(256)
void attn_combine(const float* __restrict__ Op, const float* __restrict__ lp,
                  bf16* __restrict__ att)
{
    const int i = blockIdx.x * 256 + threadIdx.x;      // over [bh][q][d/4]
    const int d4 = i & 15, q = (i >> 4) & (SEQ - 1), bh = i >> 15;
    const long halfO = (long)BATCH * NHEADS * SEQ * HDIM;
    const long rowo  = ((long)bh * SEQ + q) * HDIM;
    const float4 a = ((const float4*)(Op + rowo))[d4];
    const float4 b = ((const float4*)(Op + halfO + rowo))[d4];
    const int li = bh * SEQ + q;
    const float inv = 1.f / (lp[li] + lp[BATCH * NHEADS * SEQ + li]);
    const int bb = bh >> 4, h = bh & 15;
    union { ushort4 u4; bf16 hv[4]; } o;
    o.hv[0] = __float2bfloat16((a.x + b.x) * inv);
    o.hv[1] = __float2bfloat16((a.y + b.y) * inv);
    o.hv[2] = __float2bfloat16((a.z + b.z) * inv);
    o.hv[3] = __float2bfloat16((a.w + b.w) * inv);
    *(ushort4*)(att + ((long)bb * SEQ + q) * EMBED + h * HDIM + d4 * 4) = o.u4;
}

extern "C" void kernel_launch(void* const* d_in, const int* in_sizes, int n_in,
                              void* d_out, int out_size, void* d_ws, size_t ws_size,
                              hipStream_t stream)
{
    const float* x      = (const float*)d_in[0];
    // d_in[1] = mask: causal by construction, computed analytically — unused.
    const float* qkv_w  = (const float*)d_in[2];
    const float* qkv_b  = (const float*)d_in[3];
    const float* proj_w = (const float*)d_in[4];
    const float* proj_b = (const float*)d_in[5];
    float* out = (float*)d_out;

    const long nX  = (long)BATCH * SEQ * EMBED;     // 4,194,304
    const long nQW = 3L * EMBED * EMBED;            // 3,145,728
    const long nPW = (long)EMBED * EMBED;           // 1,048,576
    const long per = (long)BATCH * NHEADS * SEQ * HDIM;  // 4,194,304

    bf16* xw  = (bf16*)d_ws;          // x in bf16
    bf16* qwm = xw + nX;              // qkv_w bf16
    bf16* pwm = qwm + nQW;            // proj_w bf16
    bf16* qw  = pwm + nPW;            // Q [b][h][s][d]
    bf16* kw  = qw + per;             // K [b][h][s][d]
    bf16* vw  = kw + per;             // V TRANSPOSED [b][h][d][s]
    bf16* att = vw + per;             // (B*S, E) bf16 row-major
    float* Op = (float*)(att + per);  // 2 x per f32 (O partials)
    float* lp = Op + 2 * per;         // 2 x B*H*S f32 (l partials)

    // 0) f32 -> bf16 conversions (single launch)
    const int n0 = (int)(nX / 4), n1 = (int)(nQW / 4), n2 = (int)(nPW / 4);
    f2b_all<<<(n0 + n1 + n2 + 255) / 256, 256, 0, stream>>>(
        x, xw, n0, qkv_w, qwm, n1, proj_w, pwm, n2);

    // 1) QKV: (B*S,E) @ (3E,E)^T + b, scattered (V transposed); 768 blocks
    gemm_bt<1><<<dim3(3 * EMBED / 128, BATCH * SEQ / 128), 256, 0, stream>>>(
        xw, qwm, qkv_b, qw, BATCH * SEQ, 3 * EMBED, EMBED);

    // 2) barrier-free causal attention (key-split x2, XCD-affine) + combine
    attn_nf<<<dim3(BATCH * NHEADS, 32), 256, 0, stream>>>(qw, kw, vw, Op, lp);
    attn_combine<<<(int)(per / 4 / 256), 256, 0, stream>>>(Op, lp, att);

    // 3) out(f32) = att @ proj_w^T + proj_b; 256 blocks
    gemm_bt<0><<<dim3(EMBED / 128, BATCH * SEQ / 128), 256, 0, stream>>>(
        att, pwm, proj_b, out, BATCH * SEQ, EMBED, EMBED);
}